// Round 12
// baseline (551.528 us; speedup 1.0000x reference)
//
#include <hip/hip_runtime.h>
#include <stdint.h>

// Problem constants (B,T,D,H fixed by the reference)
#define B_SZ 2
#define T_SEQ 2048
#define DMODEL 1024
#define NHEAD 16
#define DKH 64
#define M_ROWS (B_SZ * T_SEQ)   // 4096

#define LDT 72    // padded LDS row stride (bf16) for legacy-path sP

#define INP_E  4194304u   // 4M elems per input tensor
#define W_E    1048576u   // 1M elems per weight

typedef __bf16 bf16x8 __attribute__((ext_vector_type(8)));
typedef float  f32x4  __attribute__((ext_vector_type(4)));

__device__ __forceinline__ unsigned short f2bf(float f) {
    unsigned u = __builtin_bit_cast(unsigned, f);
    u += 0x7fffu + ((u >> 16) & 1u);   // RNE
    return (unsigned short)(u >> 16);
}
// 8 consecutive fp32 -> 8 bf16 packed in a uint4
__device__ __forceinline__ uint4 cvt8(const float* p) {
    float4 f0 = *(const float4*)p, f1 = *(const float4*)(p + 4);
    uint4 r;
    r.x = (unsigned)f2bf(f0.x) | ((unsigned)f2bf(f0.y) << 16);
    r.y = (unsigned)f2bf(f0.z) | ((unsigned)f2bf(f0.w) << 16);
    r.z = (unsigned)f2bf(f1.x) | ((unsigned)f2bf(f1.y) << 16);
    r.w = (unsigned)f2bf(f1.z) | ((unsigned)f2bf(f1.w) << 16);
    return r;
}

// Async global->LDS. LDS dest = wave-uniform base + lane*size (m104/m108).
__device__ __forceinline__ void async16(const unsigned short* g, unsigned short* l) {
    __builtin_amdgcn_global_load_lds(
        (const __attribute__((address_space(1))) void*)g,
        (__attribute__((address_space(3))) void*)l, 16, 0, 0);
}
__device__ __forceinline__ void async4(const unsigned short* g, unsigned short* l) {
    __builtin_amdgcn_global_load_lds(
        (const __attribute__((address_space(1))) void*)g,
        (__attribute__((address_space(3))) void*)l, 4, 0, 0);
}

// One-shot fp32 -> bf16 conversion of q,k,v + 4 weights into ws.
__global__ __launch_bounds__(256) void cvt_all(
    const float* __restrict__ q, const float* __restrict__ k, const float* __restrict__ v,
    const float* __restrict__ wq, const float* __restrict__ wk,
    const float* __restrict__ wv, const float* __restrict__ wo,
    unsigned short* __restrict__ wsb)
{
    int blk = blockIdx.x;
    const float* src; unsigned short* dst; int lb;
    if      (blk < 2048) { src = q;  dst = wsb;                       lb = blk; }
    else if (blk < 4096) { src = k;  dst = wsb + INP_E;               lb = blk - 2048; }
    else if (blk < 6144) { src = v;  dst = wsb + 2 * INP_E;           lb = blk - 4096; }
    else if (blk < 6656) { src = wq; dst = wsb + 3 * INP_E;           lb = blk - 6144; }
    else if (blk < 7168) { src = wk; dst = wsb + 3 * INP_E + W_E;     lb = blk - 6656; }
    else if (blk < 7680) { src = wv; dst = wsb + 3 * INP_E + 2 * W_E; lb = blk - 7168; }
    else                 { src = wo; dst = wsb + 3 * INP_E + 3 * W_E; lb = blk - 7680; }
    size_t i = ((size_t)lb * 256 + threadIdx.x) * 8;
    *(uint4*)&dst[i] = cvt8(src + i);
}

// ---------------- m97-style GEMM core ----------------
template<int C_MODE, int MT>
__device__ __forceinline__ void gemm_core(
    const unsigned short* __restrict__ A, const unsigned short* __restrict__ W,
    const float* __restrict__ bias, void* __restrict__ C,
    int N, int K, int bx, int by,
    unsigned short* sA, unsigned short* sB)
{
    const int tid  = threadIdx.x;
    const int wave = tid >> 6, lane = tid & 63;
    const int quad = lane >> 4, l15 = lane & 15;
    const int TM = MT * 32;
    const int m0 = by * TM, n0 = bx * 128;
    const int wm = (wave & 1) * (MT * 16), wn = (wave >> 1) * 64;

    f32x4 acc[MT][4] = {};

    for (int k0 = 0; k0 < K; k0 += 64) {
        __syncthreads();                      // prev iteration's LDS reads done
        #pragma unroll
        for (int i = 0; i < MT; i++) {        // A: TM rows x 8 chunks
            int c   = tid + 256 * i;
            int row = c >> 3;
            int gk  = ((c & 7) ^ (row & 7)) * 8;
            int sb  = (wave * 64 + 256 * i) * 8;
            async16(&A[(size_t)(m0 + row) * K + k0 + gk], sA + sb);
        }
        #pragma unroll
        for (int i = 0; i < 4; i++) {         // B: 128 rows x 8 chunks
            int c   = tid + 256 * i;
            int row = c >> 3;
            int gk  = ((c & 7) ^ (row & 7)) * 8;
            int sb  = (wave * 64 + 256 * i) * 8;
            async16(&W[(size_t)(n0 + row) * K + k0 + gk], sB + sb);
        }
        __syncthreads();                      // drains vmcnt(0): data landed
        const int sw = l15 & 7;
        #pragma unroll
        for (int ks = 0; ks < 2; ks++) {
            bf16x8 af[MT], bfv[4];
            #pragma unroll
            for (int mt = 0; mt < MT; mt++)
                af[mt] = *(const bf16x8*)&sA[(wm + mt * 16 + l15) * 64 +
                                             (((ks * 4 + quad) ^ sw) * 8)];
            #pragma unroll
            for (int nt = 0; nt < 4; nt++)
                bfv[nt] = *(const bf16x8*)&sB[(wn + nt * 16 + l15) * 64 +
                                              (((ks * 4 + quad) ^ sw) * 8)];
            #pragma unroll
            for (int mt = 0; mt < MT; mt++)
                #pragma unroll
                for (int nt = 0; nt < 4; nt++)
                    acc[mt][nt] = __builtin_amdgcn_mfma_f32_16x16x32_bf16(
                        af[mt], bfv[nt], acc[mt][nt], 0, 0, 0);
        }
    }

    if (C_MODE == 2) {
        #pragma unroll
        for (int mt = 0; mt < MT; mt++) {
            #pragma unroll
            for (int r = 0; r < 4; r++) {
                int m = m0 + wm + mt * 16 + quad * 4 + r;
                float bm = bias[m];
                #pragma unroll
                for (int nt = 0; nt < 4; nt++) {
                    int n = n0 + wn + nt * 16 + l15;
                    int bb = n >> 11, t = n & 2047;
                    ((unsigned short*)C)[((size_t)bb * 1024 + m) * 2048 + t] =
                        f2bf(acc[mt][nt][r] + bm);
                }
            }
        }
    } else {
        #pragma unroll
        for (int nt = 0; nt < 4; nt++) {
            int n = n0 + wn + nt * 16 + l15;
            float bv = bias[n];
            #pragma unroll
            for (int mt = 0; mt < MT; mt++) {
                #pragma unroll
                for (int r = 0; r < 4; r++) {
                    int m = m0 + wm + mt * 16 + quad * 4 + r;   // D row = quad*4+reg
                    float val = acc[mt][nt][r] + bv;
                    if (C_MODE == 1) ((float*)C)[(size_t)m * N + n] = val;
                    else ((unsigned short*)C)[(size_t)m * N + n] = f2bf(val);
                }
            }
        }
    }
}

// Q,K,V projections + V-transpose batched: grid (256,1,3) = 768 blocks (~3/CU).
__global__ __launch_bounds__(256) void gemm_qkv(
    const unsigned short* __restrict__ Qb, const unsigned short* __restrict__ Kb,
    const unsigned short* __restrict__ Vb,
    const unsigned short* __restrict__ Wqb, const unsigned short* __restrict__ Wkb,
    const unsigned short* __restrict__ Wvb,
    const float* __restrict__ bq, const float* __restrict__ bk, const float* __restrict__ bv,
    unsigned short* __restrict__ Qp, unsigned short* __restrict__ Kp,
    unsigned short* __restrict__ Vt)
{
    __shared__ __align__(16) unsigned short sA[128 * 64];
    __shared__ __align__(16) unsigned short sB[128 * 64];
    const int z = blockIdx.z, id = blockIdx.x;
    if (z < 2) {
        gemm_core<0, 4>(z ? Kb : Qb, z ? Wkb : Wqb, z ? bk : bq, z ? Kp : Qp,
                        DMODEL, DMODEL, id & 7, id >> 3, sA, sB);
    } else {
        gemm_core<2, 4>(Wvb, Vb, bv, Vt, M_ROWS, DMODEL, id & 31, id >> 5, sA, sB);
    }
}

// Output projection: 64x128 tiles -> 512 blocks.
__global__ __launch_bounds__(256) void gemm_o(
    const unsigned short* __restrict__ AO, const unsigned short* __restrict__ Wob,
    const float* __restrict__ bo, float* __restrict__ out)
{
    __shared__ __align__(16) unsigned short sA[64 * 64];
    __shared__ __align__(16) unsigned short sB[128 * 64];
    const int id = blockIdx.x;
    gemm_core<1, 2>(AO, Wob, bo, out, DMODEL, DMODEL, id & 7, id >> 3, sA, sB);
}

// ---------------- flash attention: 4-way key split, 32 waves/CU ----------------
// Round-11 (resubmitted after broker timeout): R10 showed the wave-slot ceiling is
// the binding limit: at R=32 rows/wave with a 2-way key split the problem has only
// 4096 waves = 16/CU (chip holds 32), and no pipe exceeds 47%. This round: 4-way
// key split -> 8192 waves. 1024-thread blocks (16 waves, 4 groups x 4 waves);
// group g computes tile g of 4 per round; 8 rounds x 256 keys. Per-wave work /
// LDS traffic / MFMA / VALU totals unchanged — pure TLP doubling. LDS: 4 K + 4 V
// tiles single-buffered (64KB) + f32 mask (8KB) = 72KB -> exactly 2 blocks/CU =
// 2048 thr (chip max). Single-buffer drain covered by 2-block + 32-wave overlap.
// 4-partial merge via a 3-step LDS tree. XCD swizzle reverted (R10: FETCH 70->13MB
// but time neutral -> not the gate).
#define QBLK 128
#define KVB 64

__global__ __launch_bounds__(1024, 8) void attn_kernel(
    const unsigned short* __restrict__ Qp,
    const unsigned short* __restrict__ Kp,
    const unsigned short* __restrict__ Vt,
    const int* __restrict__ maskp,     // [B,T], nonzero = keep
    unsigned short* __restrict__ Op)
{
    __shared__ __align__(16) unsigned char sMEM[73728];
    unsigned short* sK  = (unsigned short*)sMEM;            // [4 tiles][64 key][64 d], 32KB
    unsigned short* sV  = (unsigned short*)(sMEM + 32768);  // [4 tiles][64 d][64 permkey], 32KB
    float*          smf = (float*)(sMEM + 65536);           // [2048] mask add table, 8KB

    const int tid  = threadIdx.x;
    const int wave = tid >> 6, lane = tid & 63;
    const int g    = wave >> 2, wl = wave & 3;     // group 0..3, wave-in-group 0..3
    const int quad = lane >> 4, l15 = lane & 15;
    const int qblk = blockIdx.x, h = blockIdx.y, b = blockIdx.z;

    const float SCL2 = 0.125f * 1.44269504089f;   // 1/sqrt(DK) * log2(e)
    const float MNEG = -30000.f;                  // exp2(-30000+x) == 0

    // Q fragments (B-operand: col=q=l15, k=d=quad*8+j), rows wl*32 + mt*16 + l15
    bf16x8 aq[2][2];
    #pragma unroll
    for (int mt = 0; mt < 2; mt++) {
        const int qrow = qblk * QBLK + wl * 32 + mt * 16 + l15;
        const unsigned short* qptr =
            Qp + (size_t)(b * T_SEQ + qrow) * DMODEL + h * DKH + quad * 8;
        aq[mt][0] = *(const bf16x8*)qptr;
        aq[mt][1] = *(const bf16x8*)(qptr + 32);
    }

    const unsigned short* Kb_ = Kp + (size_t)b * T_SEQ * DMODEL + h * DKH;
    const unsigned short* VtB = Vt + ((size_t)b * DMODEL + h * DKH) * T_SEQ;

    // ---- staging address precompute (loop-invariant) ----
    // K: 2 width-16 loads/thread/round (4 tiles x 8KB = 2048 chunks over 1024 thr).
    int kOff[2], kSb[2];
    #pragma unroll
    for (int i = 0; i < 2; i++) {
        int c = tid + 1024 * i;
        int tile = c >> 9, cc = c & 511;
        int row = cc >> 3;
        int gk = ((cc & 7) ^ (row & 7)) * 8;
        kOff[i] = (tile * 64 + row) * DMODEL + gk;        // + rr*256*DMODEL at use
        kSb[i]  = (wave * 64 + 1024 * i) * 8;             // wave-uniform dest (shorts)
    }
    // V: 8 width-4 loads/thread/round into the PERMUTED layout (4 x 8KB tiles).
    int vOff[8], vSb[8];
    #pragma unroll
    for (int i = 0; i < 8; i++) {
        int c    = tid + 1024 * i;                        // 4B-chunk id 0..8191
        int P    = c * 4;                                 // byte pos in 32KB V region
        int tile = P >> 13;
        int rp   = P & 8191;
        int row  = rp >> 7;                               // d row
        int cb   = (rp >> 4) & 7;                         // stored chunk
        int slot = (rp >> 2) & 3;                         // 4B slot in chunk
        int cc2  = cb ^ (row & 7);                        // logical perm chunk
        int f    = cc2 * 4 + slot;                        // perm 4B index 0..31
        int g2   = ((f >> 4) << 1) | ((f >> 1) & 1);
        int qq   = (f >> 2) & 3;
        int r2   = (f & 1) * 2;
        int keyoff = g2 * 16 + qq * 4 + r2;
        vOff[i] = row * T_SEQ + tile * 64 + keyoff;       // + rr*256 at use
        vSb[i]  = (wave * 64 + 1024 * i) * 2;             // wave-uniform dest (shorts)
    }

    f32x4 O[2][4] = {};
    float l_r[2] = {0.f, 0.f};

    // ---- prologue: stage round 0; expand mask ----
    #pragma unroll
    for (int i = 0; i < 2; i++)
        async16(&Kb_[kOff[i]], sK + kSb[i]);
    #pragma unroll
    for (int i = 0; i < 8; i++)
        async4(&VtB[vOff[i]], sV + vSb[i]);
    #pragma unroll
    for (int j = 0; j < 2; j++) {
        int i = tid + 1024 * j;
        smf[i] = maskp[b * T_SEQ + i] ? 0.f : MNEG;
    }
    __syncthreads();   // drains round-0 stage; smf visible

    const int sw = l15 & 7;
    const unsigned short* sKp = sK + g * 4096;   // this group's K tile
    const unsigned short* sVp = sV + g * 4096;   // this group's V tile

    for (int rr = 0; rr < T_SEQ / (4 * KVB); ++rr) {   // 8 rounds, 4 tiles each
        const int s0 = rr * 256 + g * KVB;

        // ---- S^T = K Q^T : row = key = kt*16+quad*4+r, col = q = mt*16+l15 ----
        f32x4 ST[2][4];
        __builtin_amdgcn_s_setprio(1);
        #pragma unroll
        for (int kt = 0; kt < 4; kt++) {
            const unsigned short* kr = &sKp[(kt * 16 + l15) * 64];
            const bf16x8 kf0 = *(const bf16x8*)&kr[(quad ^ sw) * 8];
            const bf16x8 kf1 = *(const bf16x8*)&kr[((quad + 4) ^ sw) * 8];
            #pragma unroll
            for (int mt = 0; mt < 2; mt++) {
                f32x4 z = {};
                z = __builtin_amdgcn_mfma_f32_16x16x32_bf16(kf0, aq[mt][0], z, 0, 0, 0);
                z = __builtin_amdgcn_mfma_f32_16x16x32_bf16(kf1, aq[mt][1], z, 0, 0, 0);
                ST[mt][kt] = z;
            }
        }
        __builtin_amdgcn_s_setprio(0);

        // ---- softmax fully in-register; pack P^T into B-fragments ----
        bf16x8 pb[2][2];
        #pragma unroll
        for (int kt = 0; kt < 4; kt++) {
            float4 m4 = *(const float4*)&smf[s0 + kt * 16 + quad * 4];  // broadcast b128
            float ma[4] = {m4.x, m4.y, m4.z, m4.w};
            #pragma unroll
            for (int mt = 0; mt < 2; mt++) {
                #pragma unroll
                for (int r = 0; r < 4; r++) {
                    float p = __builtin_amdgcn_exp2f(fmaf(ST[mt][kt][r], SCL2, ma[r]));
                    l_r[mt] += p;
                    pb[mt][kt >> 1][(kt & 1) * 4 + r] = (__bf16)p;   // key kt*16+quad*4+r
                }
            }
        }

        // ---- O^T += V^T P^T (A = permuted V^T rows d, B = in-register P^T) ----
        __builtin_amdgcn_s_setprio(1);
        #pragma unroll
        for (int nt = 0; nt < 4; nt++) {
            const unsigned short* vr = &sVp[(nt * 16 + l15) * 64];
            const bf16x8 vf0 = *(const bf16x8*)&vr[(quad ^ sw) * 8];
            const bf16x8 vf1 = *(const bf16x8*)&vr[((quad + 4) ^ sw) * 8];
            #pragma unroll
            for (int mt = 0; mt < 2; mt++) {
                O[mt][nt] = __builtin_amdgcn_mfma_f32_16x16x32_bf16(
                    vf0, pb[mt][0], O[mt][nt], 0, 0, 0);
                O[mt][nt] = __builtin_amdgcn_mfma_f32_16x16x32_bf16(
                    vf1, pb[mt][1], O[mt][nt], 0, 0, 0);
            }
        }
        __builtin_amdgcn_s_setprio(0);

        __syncthreads();   // all reads of this round's tiles done
        if (rr + 1 < T_SEQ / (4 * KVB)) {
            #pragma unroll
            for (int i = 0; i < 2; i++)
                async16(&Kb_[(size_t)(rr + 1) * 256 * DMODEL + kOff[i]], sK + kSb[i]);
            #pragma unroll
            for (int i = 0; i < 8; i++)
                async4(&VtB[(size_t)(rr + 1) * 256 + vOff[i]], sV + vSb[i]);
            __syncthreads();   // drain: next round's tiles landed
        }
    }

    // ---- l: sum across quads (q = mt*16 + l15 lives in 4 quad-copies) ----
    #pragma unroll
    for (int mt = 0; mt < 2; mt++) {
        float l = l_r[mt];
        l += __shfl_xor(l, 16);
        l += __shfl_xor(l, 32);
        l_r[mt] = l;
    }

    // ---- 4-partial merge via LDS tree: OM0/OM1 f32[128][65] + LM0/LM1[128] ----
    float* OM0 = (float*)sMEM;             // 33280 B
    float* OM1 = (float*)(sMEM + 33280);   // 33280 B
    float* LM0 = (float*)(sMEM + 66560);   // 512 B
    float* LM1 = (float*)(sMEM + 67072);   // 512 B
    // phase 1: g1 -> OM0, g3 -> OM1
    if (g == 1 || g == 3) {
        float* OM = (g == 1) ? OM0 : OM1;
        float* LM = (g == 1) ? LM0 : LM1;
        #pragma unroll
        for (int mt = 0; mt < 2; mt++) {
            int row = wl * 32 + mt * 16 + l15;
            if (quad == 0) LM[row] = l_r[mt];
            #pragma unroll
            for (int nt = 0; nt < 4; nt++)
                #pragma unroll
                for (int r = 0; r < 4; r++)
                    OM[row * 65 + nt * 16 + quad * 4 + r] = O[mt][nt][r];
        }
    }
    __syncthreads();
    // phase 2: g0 += OM0, g2 += OM1
    if (g == 0 || g == 2) {
        float* OM = (g == 0) ? OM0 : OM1;
        float* LM = (g == 0) ? LM0 : LM1;
        #pragma unroll
        for (int mt = 0; mt < 2; mt++) {
            int row = wl * 32 + mt * 16 + l15;
            l_r[mt] += LM[row];
            #pragma unroll
            for (int nt = 0; nt < 4; nt++)
                #pragma unroll
                for (int r = 0; r < 4; r++)
                    O[mt][nt][r] += OM[row * 65 + nt * 16 + quad * 4 + r];
        }
    }
    __syncthreads();
    // phase 3: g2 -> OM0
    if (g == 2) {
        #pragma unroll
        for (int mt = 0; mt < 2; mt++) {
            int row = wl * 32 + mt * 16 + l15;
            if (quad == 0) LM0[row] = l_r[mt];
            #pragma unroll
            for (int nt = 0; nt < 4; nt++)
                #pragma unroll
                for (int r = 0; r < 4; r++)
                    OM0[row * 65 + nt * 16 + quad * 4 + r] = O[mt][nt][r];
        }
    }
    __syncthreads();
    // phase 4: g0 merges, normalizes, stores
    if (g == 0) {
        #pragma unroll
        for (int mt = 0; mt < 2; mt++) {
            int row = wl * 32 + mt * 16 + l15;
            float inv = 1.0f / fmaxf(l_r[mt] + LM0[row], 1e-30f);
            int qg = qblk * QBLK + row;
            unsigned short* op = Op + (size_t)(b * T_SEQ + qg) * DMODEL + h * DKH;
            #pragma unroll
            for (int nt = 0; nt < 4; nt++) {
                ushort4 w;
                w.x = f2bf((O[mt][nt][0] + OM0[row * 65 + nt * 16 + quad * 4 + 0]) * inv);
                w.y = f2bf((O[mt][nt][1] + OM0[row * 65 + nt * 16 + quad * 4 + 1]) * inv);
                w.z = f2bf((O[mt][nt][2] + OM0[row * 65 + nt * 16 + quad * 4 + 2]) * inv);
                w.w = f2bf((O[mt][nt][3] + OM0[row * 65 + nt * 16 + quad * 4 + 3]) * inv);
                *(ushort4*)&op[nt * 16 + quad * 4] = w;
            }
        }
    }
}

// ---------------- legacy fp32-staging GEMM (fallback path only) ----------------
template<int A_BF16, int W_BF16, int C_MODE>
__global__ __launch_bounds__(256) void gemm_bt_cvt(
    const void* __restrict__ A_, const void* __restrict__ W_,
    const float* __restrict__ bias, void* __restrict__ C_,
    int M, int N, int K)
{
    __shared__ __align__(16) unsigned short sA[128 * LDT];
    __shared__ __align__(16) unsigned short sB[128 * LDT];
    const int tid  = threadIdx.x;
    const int wave = tid >> 6, lane = tid & 63;
    const int quad = lane >> 4, l15 = lane & 15;
    const int m0 = blockIdx.y * 128, n0 = blockIdx.x * 128;
    const int wm = (wave & 1) * 64, wn = (wave >> 1) * 64;
    f32x4 acc[4][4] = {};
    for (int k0 = 0; k0 < K; k0 += 64) {
        __syncthreads();
        #pragma unroll
        for (int i = 0; i < 4; i++) {
            int c = tid + 256 * i;
            int row = c >> 3, koff = (c & 7) * 8;
            if (A_BF16)
                *(uint4*)&sA[row * LDT + koff] =
                    *(const uint4*)&((const unsigned short*)A_)[(size_t)(m0 + row) * K + k0 + koff];
            else
                *(uint4*)&sA[row * LDT + koff] =
                    cvt8((const float*)A_ + (size_t)(m0 + row) * K + k0 + koff);
            if (W_BF16)
                *(uint4*)&sB[row * LDT + koff] =
                    *(const uint4*)&((const unsigned short*)W_)[(size_t)(n0 + row) * K + k0 + koff];
            else
                *(uint4*)&sB[row * LDT + koff] =
                    cvt8((const float*)W_ + (size_t)(n0 + row) * K + k0 + koff);
        }
        __syncthreads();
        #pragma unroll
        for (int ks = 0; ks < 2; ks++) {
            bf16x8 af[4], bfr[4];
            #pragma unroll
            for (int mt = 0; mt < 4; mt++)
                af[mt] = *(const bf16x8*)&sA[(wm + mt * 16 + l15) * LDT + ks * 32 + quad * 8];
            #pragma unroll
            for (int nt = 0; nt < 4; nt++)
                bfr[nt] = *(const bf16x8*)&sB[(wn + nt * 16 + l15) * LDT + ks * 32 + quad * 8];
            #pragma unroll
            for (int mt = 0; mt < 4; mt++)
                #pragma unroll
                for (int nt = 0; nt < 4; nt++)
                    acc[mt][nt] = __builtin_amdgcn_mfma_f32_16x16x32_bf16(
                        af[mt], bfr[nt], acc[mt][nt], 0, 0, 0);
        }
    }
    if (C_MODE == 2) {
        #pragma unroll
        for (int mt = 0; mt < 4; mt++)
            #pragma unroll
            for (int r = 0; r < 4; r++) {
                int m = m0 + wm + mt * 16 + quad * 4 + r;
                float bm = bias[m];
                #pragma unroll
                for (int nt = 0; nt < 4; nt++) {
                    int n = n0 + wn + nt * 16 + l15;
                    int bb = n >> 11, t = n & 2047;
                    ((unsigned short*)C_)[((size_t)bb * 1024 + m) * 2048 + t] =
                        f2bf(acc[mt][nt][r] + bm);
                }
            }
    } else {
        #pragma unroll
        for (int nt = 0; nt < 4; nt++) {
            int n = n0 + wn + nt * 16 + l15;
            float bv = bias[n];
            #pragma unroll
            for (int mt = 0; mt < 4; mt++)
                #pragma unroll
                for (int r = 0; r < 4; r++) {
                    int m = m0 + wm + mt * 16 + quad * 4 + r;
                    float val = acc[mt][nt][r] + bv;
                    if (C_MODE == 1) ((float*)C_)[(size_t)m * N + n] = val;
                    else ((unsigned short*)C_)[(size_t)m * N + n] = f2bf(val);
                }
        }
    }
}

extern "C" void kernel_launch(void* const* d_in, const int* in_sizes, int n_in,
                              void* d_out, int out_size, void* d_ws, size_t ws_size,
                              hipStream_t stream)
{
    const float* q  = (const float*)d_in[0];
    const float* k  = (const float*)d_in[1];
    const float* v  = (const float*)d_in[2];
    const int*   mk = (const int*)d_in[3];
    const float* Wq = (const float*)d_in[4];
    const float* bq = (const float*)d_in[5];
    const float* Wk = (const float*)d_in[6];
    const float* bk = (const float*)d_in[7];
    const float* Wv = (const float*)d_in[8];
    const float* bv = (const float*)d_in[9];
    const float* Wo = (const float*)d_in[10];
    const float* bo = (const float*)d_in[11];
    float* out = (float*)d_out;

    unsigned short* wsb = (unsigned short*)d_ws;
    const dim3 gA(T_SEQ / QBLK, NHEAD, B_SZ);   // 16 x 16 x 2 = 512 blocks of 1024 thr

    if (ws_size >= (size_t)64 * 1024 * 1024) {
        // Path A: pre-convert to bf16; m97-style global_load_lds GEMMs.
        unsigned short* Qb  = wsb;
        unsigned short* Kb  = wsb + INP_E;
        unsigned short* Vb  = wsb + 2 * INP_E;
        unsigned short* Wqb = wsb + 3 * INP_E;
        unsigned short* Wkb = wsb + 3 * INP_E + W_E;
        unsigned short* Wvb = wsb + 3 * INP_E + 2 * W_E;
        unsigned short* Wob = wsb + 3 * INP_E + 3 * W_E;
        unsigned short* Qp  = wsb + 4 * INP_E;
        unsigned short* Kp  = wsb + 5 * INP_E;
        unsigned short* Vt  = wsb + 6 * INP_E;
        unsigned short* AO  = wsb + 7 * INP_E;       // end = 64MB

        cvt_all<<<8192, 256, 0, stream>>>(q, k, v, Wq, Wk, Wv, Wo, wsb);
        gemm_qkv<<<dim3(256, 1, 3), 256, 0, stream>>>(
            Qb, Kb, Vb, Wqb, Wkb, Wvb, bq, bk, bv, Qp, Kp, Vt);
        attn_kernel<<<gA, 1024, 0, stream>>>(Qp, Kp, Vt, mk, AO);
        gemm_o<<<dim3(512, 1, 1), 256, 0, stream>>>(AO, Wob, bo, out);
    } else {
        // Path C fallback: in-GEMM convert (32MB ws), legacy kernels.
        unsigned short* Qp = wsb;
        unsigned short* Kp = wsb + INP_E;
        unsigned short* Vt = wsb + 2 * INP_E;
        unsigned short* AO = wsb + 3 * INP_E;
        const dim3 gN(DMODEL / 128, M_ROWS / 128);
        const dim3 gV(M_ROWS / 128, DMODEL / 128);
        gemm_bt_cvt<0, 0, 0><<<gN, 256, 0, stream>>>(q, Wq, bq, Qp, M_ROWS, DMODEL, DMODEL);
        gemm_bt_cvt<0, 0, 0><<<gN, 256, 0, stream>>>(k, Wk, bk, Kp, M_ROWS, DMODEL, DMODEL);
        gemm_bt_cvt<0, 0, 2><<<gV, 256, 0, stream>>>(Wv, v, bv, Vt, DMODEL, M_ROWS, DMODEL);
        attn_kernel<<<gA, 1024, 0, stream>>>(Qp, Kp, Vt, mk, AO);
        gemm_bt_cvt<1, 0, 1><<<gN, 256, 0, stream>>>(AO, Wo, bo, out, M_ROWS, DMODEL, DMODEL);
    }
}

// Round 20
// 225.401 us; speedup vs baseline: 2.4469x; 2.4469x over previous
//
#include <hip/hip_runtime.h>
#include <stdint.h>

// Problem constants (B,T,D,H fixed by the reference)
#define B_SZ 2
#define T_SEQ 2048
#define DMODEL 1024
#define NHEAD 16
#define DKH 64
#define M_ROWS (B_SZ * T_SEQ)   // 4096

#define LDT 72    // padded LDS row stride (bf16) for legacy-path sP

#define INP_E  4194304u   // 4M elems per input tensor
#define W_E    1048576u   // 1M elems per weight

typedef __bf16 bf16x8 __attribute__((ext_vector_type(8)));
typedef float  f32x4  __attribute__((ext_vector_type(4)));

__device__ __forceinline__ unsigned short f2bf(float f) {
    unsigned u = __builtin_bit_cast(unsigned, f);
    u += 0x7fffu + ((u >> 16) & 1u);   // RNE
    return (unsigned short)(u >> 16);
}
// 8 consecutive fp32 -> 8 bf16 packed in a uint4
__device__ __forceinline__ uint4 cvt8(const float* p) {
    float4 f0 = *(const float4*)p, f1 = *(const float4*)(p + 4);
    uint4 r;
    r.x = (unsigned)f2bf(f0.x) | ((unsigned)f2bf(f0.y) << 16);
    r.y = (unsigned)f2bf(f0.z) | ((unsigned)f2bf(f0.w) << 16);
    r.z = (unsigned)f2bf(f1.x) | ((unsigned)f2bf(f1.y) << 16);
    r.w = (unsigned)f2bf(f1.z) | ((unsigned)f2bf(f1.w) << 16);
    return r;
}

// Async global->LDS. LDS dest = wave-uniform base + lane*size (m104/m108).
__device__ __forceinline__ void async16(const unsigned short* g, unsigned short* l) {
    __builtin_amdgcn_global_load_lds(
        (const __attribute__((address_space(1))) void*)g,
        (__attribute__((address_space(3))) void*)l, 16, 0, 0);
}
__device__ __forceinline__ void async4(const unsigned short* g, unsigned short* l) {
    __builtin_amdgcn_global_load_lds(
        (const __attribute__((address_space(1))) void*)g,
        (__attribute__((address_space(3))) void*)l, 4, 0, 0);
}

// One-shot fp32 -> bf16 conversion of q,k,v + 4 weights into ws.
// 2048 blocks, 4 virtual-block iterations each (G11 grid cap + ILP).
__global__ __launch_bounds__(256) void cvt_all(
    const float* __restrict__ q, const float* __restrict__ k, const float* __restrict__ v,
    const float* __restrict__ wq, const float* __restrict__ wk,
    const float* __restrict__ wv, const float* __restrict__ wo,
    unsigned short* __restrict__ wsb)
{
    for (int blk = blockIdx.x; blk < 8192; blk += 2048) {
        const float* src; unsigned short* dst; int lb;
        if      (blk < 2048) { src = q;  dst = wsb;                       lb = blk; }
        else if (blk < 4096) { src = k;  dst = wsb + INP_E;               lb = blk - 2048; }
        else if (blk < 6144) { src = v;  dst = wsb + 2 * INP_E;           lb = blk - 4096; }
        else if (blk < 6656) { src = wq; dst = wsb + 3 * INP_E;           lb = blk - 6144; }
        else if (blk < 7168) { src = wk; dst = wsb + 3 * INP_E + W_E;     lb = blk - 6656; }
        else if (blk < 7680) { src = wv; dst = wsb + 3 * INP_E + 2 * W_E; lb = blk - 7168; }
        else                 { src = wo; dst = wsb + 3 * INP_E + 3 * W_E; lb = blk - 7680; }
        size_t i = ((size_t)lb * 256 + threadIdx.x) * 8;
        *(uint4*)&dst[i] = cvt8(src + i);
    }
}

// ---------------- m97-style GEMM core ----------------
template<int C_MODE, int MT>
__device__ __forceinline__ void gemm_core(
    const unsigned short* __restrict__ A, const unsigned short* __restrict__ W,
    const float* __restrict__ bias, void* __restrict__ C,
    int N, int K, int bx, int by,
    unsigned short* sA, unsigned short* sB)
{
    const int tid  = threadIdx.x;
    const int wave = tid >> 6, lane = tid & 63;
    const int quad = lane >> 4, l15 = lane & 15;
    const int TM = MT * 32;
    const int m0 = by * TM, n0 = bx * 128;
    const int wm = (wave & 1) * (MT * 16), wn = (wave >> 1) * 64;

    f32x4 acc[MT][4] = {};

    for (int k0 = 0; k0 < K; k0 += 64) {
        __syncthreads();                      // prev iteration's LDS reads done
        #pragma unroll
        for (int i = 0; i < MT; i++) {        // A: TM rows x 8 chunks
            int c   = tid + 256 * i;
            int row = c >> 3;
            int gk  = ((c & 7) ^ (row & 7)) * 8;
            int sb  = (wave * 64 + 256 * i) * 8;
            async16(&A[(size_t)(m0 + row) * K + k0 + gk], sA + sb);
        }
        #pragma unroll
        for (int i = 0; i < 4; i++) {         // B: 128 rows x 8 chunks
            int c   = tid + 256 * i;
            int row = c >> 3;
            int gk  = ((c & 7) ^ (row & 7)) * 8;
            int sb  = (wave * 64 + 256 * i) * 8;
            async16(&W[(size_t)(n0 + row) * K + k0 + gk], sB + sb);
        }
        __syncthreads();                      // drains vmcnt(0): data landed
        const int sw = l15 & 7;
        #pragma unroll
        for (int ks = 0; ks < 2; ks++) {
            bf16x8 af[MT], bfv[4];
            #pragma unroll
            for (int mt = 0; mt < MT; mt++)
                af[mt] = *(const bf16x8*)&sA[(wm + mt * 16 + l15) * 64 +
                                             (((ks * 4 + quad) ^ sw) * 8)];
            #pragma unroll
            for (int nt = 0; nt < 4; nt++)
                bfv[nt] = *(const bf16x8*)&sB[(wn + nt * 16 + l15) * 64 +
                                              (((ks * 4 + quad) ^ sw) * 8)];
            #pragma unroll
            for (int mt = 0; mt < MT; mt++)
                #pragma unroll
                for (int nt = 0; nt < 4; nt++)
                    acc[mt][nt] = __builtin_amdgcn_mfma_f32_16x16x32_bf16(
                        af[mt], bfv[nt], acc[mt][nt], 0, 0, 0);
        }
    }

    if (C_MODE == 2) {
        #pragma unroll
        for (int mt = 0; mt < MT; mt++) {
            #pragma unroll
            for (int r = 0; r < 4; r++) {
                int m = m0 + wm + mt * 16 + quad * 4 + r;
                float bm = bias[m];
                #pragma unroll
                for (int nt = 0; nt < 4; nt++) {
                    int n = n0 + wn + nt * 16 + l15;
                    int bb = n >> 11, t = n & 2047;
                    ((unsigned short*)C)[((size_t)bb * 1024 + m) * 2048 + t] =
                        f2bf(acc[mt][nt][r] + bm);
                }
            }
        }
    } else {
        #pragma unroll
        for (int nt = 0; nt < 4; nt++) {
            int n = n0 + wn + nt * 16 + l15;
            float bv = bias[n];
            #pragma unroll
            for (int mt = 0; mt < MT; mt++) {
                #pragma unroll
                for (int r = 0; r < 4; r++) {
                    int m = m0 + wm + mt * 16 + quad * 4 + r;   // D row = quad*4+reg
                    float val = acc[mt][nt][r] + bv;
                    if (C_MODE == 1) ((float*)C)[(size_t)m * N + n] = val;
                    else ((unsigned short*)C)[(size_t)m * N + n] = f2bf(val);
                }
            }
        }
    }
}

// Q,K,V projections + V-transpose batched: grid (256,1,3) = 768 blocks (~3/CU).
__global__ __launch_bounds__(256) void gemm_qkv(
    const unsigned short* __restrict__ Qb, const unsigned short* __restrict__ Kb,
    const unsigned short* __restrict__ Vb,
    const unsigned short* __restrict__ Wqb, const unsigned short* __restrict__ Wkb,
    const unsigned short* __restrict__ Wvb,
    const float* __restrict__ bq, const float* __restrict__ bk, const float* __restrict__ bv,
    unsigned short* __restrict__ Qp, unsigned short* __restrict__ Kp,
    unsigned short* __restrict__ Vt)
{
    __shared__ __align__(16) unsigned short sA[128 * 64];
    __shared__ __align__(16) unsigned short sB[128 * 64];
    const int z = blockIdx.z, id = blockIdx.x;
    if (z < 2) {
        gemm_core<0, 4>(z ? Kb : Qb, z ? Wkb : Wqb, z ? bk : bq, z ? Kp : Qp,
                        DMODEL, DMODEL, id & 7, id >> 3, sA, sB);
    } else {
        gemm_core<2, 4>(Wvb, Vb, bv, Vt, M_ROWS, DMODEL, id & 31, id >> 5, sA, sB);
    }
}

// Output projection: 64x128 tiles -> 512 blocks.
__global__ __launch_bounds__(256) void gemm_o(
    const unsigned short* __restrict__ AO, const unsigned short* __restrict__ Wob,
    const float* __restrict__ bo, float* __restrict__ out)
{
    __shared__ __align__(16) unsigned short sA[64 * 64];
    __shared__ __align__(16) unsigned short sB[128 * 64];
    const int id = blockIdx.x;
    gemm_core<1, 2>(AO, Wob, bo, out, DMODEL, DMODEL, id & 7, id >> 3, sA, sB);
}

// ---------------- flash attention: in-register P^T + DOUBLE-BUFFERED rounds ----------------
// Round-19 (resubmitted after broker failure x7; clean re-emit): REVERT to the R9
// structure (last clean measurement: 52.3 us, VGPR 64). R12's 4-way split regressed
// 10x: __launch_bounds__(1024,8) capped VGPR at 32 for a ~100-VGPR body -> 1.78 GB
// scratch spill traffic per dispatch. Lesson: 8 waves/SIMD (<=64 VGPR) is
// unreachable for this body; 16 waves/CU + dbuf + in-register P^T is the plateau
// (~52 us). Structure: 2-way key split (groups of 4 waves on even/odd tiles), K/V
// rounds double-buffered, zero-shuffle in-reg P^T via swapped QK^T + key-permuted V,
// merge through dead LDS.
#define QBLK 128
#define KVB 64

__global__ __launch_bounds__(512, 4) void attn_kernel(
    const unsigned short* __restrict__ Qp,
    const unsigned short* __restrict__ Kp,
    const unsigned short* __restrict__ Vt,
    const int* __restrict__ maskp,     // [B,T], nonzero = keep
    unsigned short* __restrict__ Op)
{
    __shared__ __align__(16) unsigned char sMEM[73728];
    unsigned short* sK  = (unsigned short*)sMEM;            // [2 buf][2 tiles][64 key][64 d], 32KB
    unsigned short* sV  = (unsigned short*)(sMEM + 32768);  // [2 buf][2 tiles][64 d][64 permkey], 32KB
    float*          smf = (float*)(sMEM + 65536);           // [2048] mask add table, 8KB

    const int tid  = threadIdx.x;
    const int wave = tid >> 6, lane = tid & 63;
    const int g    = wave >> 2, wl = wave & 3;
    const int quad = lane >> 4, l15 = lane & 15;
    const int qblk = blockIdx.x, h = blockIdx.y, b = blockIdx.z;

    const float SCL2 = 0.125f * 1.44269504089f;   // 1/sqrt(DK) * log2(e)
    const float MNEG = -30000.f;                  // exp2(-30000+x) == 0

    // Q fragments (B-operand: col=q=l15, k=d=quad*8+j), rows wl*32 + mt*16 + l15
    bf16x8 aq[2][2];
    #pragma unroll
    for (int mt = 0; mt < 2; mt++) {
        const int qrow = qblk * QBLK + wl * 32 + mt * 16 + l15;
        const unsigned short* qptr =
            Qp + (size_t)(b * T_SEQ + qrow) * DMODEL + h * DKH + quad * 8;
        aq[mt][0] = *(const bf16x8*)qptr;
        aq[mt][1] = *(const bf16x8*)(qptr + 32);
    }

    const unsigned short* Kb_ = Kp + (size_t)b * T_SEQ * DMODEL + h * DKH;
    const unsigned short* VtB = Vt + ((size_t)b * DMODEL + h * DKH) * T_SEQ;

    // ---- staging address precompute (loop-invariant) ----
    // K: 2 width-16 loads/thread/round (2 tiles x 8KB).
    int kOff[2], kSb[2];
    #pragma unroll
    for (int i = 0; i < 2; i++) {
        int c = tid + 512 * i;
        int tile = c >> 9, cc = c & 511;
        int row = cc >> 3;
        int gk = ((cc & 7) ^ (row & 7)) * 8;
        kOff[i] = (tile * 64 + row) * DMODEL + gk;        // + rr*128*DMODEL at use
        kSb[i]  = (wave * 64 + 512 * i) * 8;              // element offset within one buf
    }
    // V: 8 width-4 loads/thread/round into the PERMUTED layout.
    int vOff[8], vSb[8];
    #pragma unroll
    for (int i = 0; i < 8; i++) {
        int P    = wave * 2048 + i * 256 + lane * 4;      // byte pos in one 16KB V buf
        int tile = P >> 13;
        int rp   = P & 8191;
        int row  = rp >> 7;                               // d row
        int cb   = (rp >> 4) & 7;                         // stored chunk
        int slot = (rp >> 2) & 3;                         // 4B slot in chunk
        int c    = cb ^ (row & 7);                        // logical perm chunk
        int f    = c * 4 + slot;                          // perm 4B index 0..31
        int g2   = ((f >> 4) << 1) | ((f >> 1) & 1);
        int qq   = (f >> 2) & 3;
        int r2   = (f & 1) * 2;
        int keyoff = g2 * 16 + qq * 4 + r2;
        vOff[i] = row * T_SEQ + tile * 64 + keyoff;       // + rr*128 at use
        vSb[i]  = (wave * 2048 + i * 256) >> 1;           // wave-uniform dest (shorts)
    }

    f32x4 O[2][4] = {};
    float l_r[2] = {0.f, 0.f};

    // ---- prologue: stage round 0 into buf 0; expand mask ----
    #pragma unroll
    for (int i = 0; i < 2; i++)
        async16(&Kb_[kOff[i]], sK + kSb[i]);
    #pragma unroll
    for (int i = 0; i < 8; i++)
        async4(&VtB[vOff[i]], sV + vSb[i]);
    #pragma unroll
    for (int j = 0; j < 4; j++) {
        int i = tid + 512 * j;
        smf[i] = maskp[b * T_SEQ + i] ? 0.f : MNEG;
    }
    __syncthreads();   // drains round-0 stage; smf visible

    const int sw = l15 & 7;
    for (int rr = 0; rr < T_SEQ / (2 * KVB); ++rr) {   // 16 rounds, 2 tiles each
        const int cur = rr & 1;
        // ---- issue round rr+1's stage into the other buffer (overlaps compute) ----
        if (rr + 1 < T_SEQ / (2 * KVB)) {
            const int nb = cur ^ 1;
            #pragma unroll
            for (int i = 0; i < 2; i++)
                async16(&Kb_[(size_t)(rr + 1) * 128 * DMODEL + kOff[i]],
                        sK + nb * 8192 + kSb[i]);
            #pragma unroll
            for (int i = 0; i < 8; i++)
                async4(&VtB[(size_t)(rr + 1) * 128 + vOff[i]],
                       sV + nb * 8192 + vSb[i]);
        }

        const unsigned short* sKp = sK + cur * 8192 + g * 4096;
        const unsigned short* sVp = sV + cur * 8192 + g * 4096;
        const int s0 = (2 * rr + g) * KVB;

        // ---- S^T = K Q^T : row = key = kt*16+quad*4+r, col = q = mt*16+l15 ----
        f32x4 ST[2][4];
        __builtin_amdgcn_s_setprio(1);
        #pragma unroll
        for (int kt = 0; kt < 4; kt++) {
            const unsigned short* kr = &sKp[(kt * 16 + l15) * 64];
            const bf16x8 kf0 = *(const bf16x8*)&kr[(quad ^ sw) * 8];
            const bf16x8 kf1 = *(const bf16x8*)&kr[((quad + 4) ^ sw) * 8];
            #pragma unroll
            for (int mt = 0; mt < 2; mt++) {
                f32x4 z = {};
                z = __builtin_amdgcn_mfma_f32_16x16x32_bf16(kf0, aq[mt][0], z, 0, 0, 0);
                z = __builtin_amdgcn_mfma_f32_16x16x32_bf16(kf1, aq[mt][1], z, 0, 0, 0);
                ST[mt][kt] = z;
            }
        }
        __builtin_amdgcn_s_setprio(0);

        // ---- softmax fully in-register; pack P^T into B-fragments ----
        bf16x8 pb[2][2];
        #pragma unroll
        for (int kt = 0; kt < 4; kt++) {
            float4 m4 = *(const float4*)&smf[s0 + kt * 16 + quad * 4];  // broadcast b128
            float ma[4] = {m4.x, m4.y, m4.z, m4.w};
            #pragma unroll
            for (int mt = 0; mt < 2; mt++) {
                #pragma unroll
                for (int r = 0; r < 4; r++) {
                    float p = __builtin_amdgcn_exp2f(fmaf(ST[mt][kt][r], SCL2, ma[r]));
                    l_r[mt] += p;
                    pb[mt][kt >> 1][(kt & 1) * 4 + r] = (__bf16)p;   // key (kt)*16+quad*4+r
                }
            }
        }

        // ---- O^T += V^T P^T (A = permuted V^T rows d, B = in-register P^T) ----
        __builtin_amdgcn_s_setprio(1);
        #pragma unroll
        for (int nt = 0; nt < 4; nt++) {
            const unsigned short* vr = &sVp[(nt * 16 + l15) * 64];
            const bf16x8 vf0 = *(const bf16x8*)&vr[(quad ^ sw) * 8];
            const bf16x8 vf1 = *(const bf16x8*)&vr[((quad + 4) ^ sw) * 8];
            #pragma unroll
            for (int mt = 0; mt < 2; mt++) {
                O[mt][nt] = __builtin_amdgcn_mfma_f32_16x16x32_bf16(
                    vf0, pb[mt][0], O[mt][nt], 0, 0, 0);
                O[mt][nt] = __builtin_amdgcn_mfma_f32_16x16x32_bf16(
                    vf1, pb[mt][1], O[mt][nt], 0, 0, 0);
            }
        }
        __builtin_amdgcn_s_setprio(0);

        // single barrier: all reads of buf[cur] done before round rr+2 overwrites it;
        // also drains the rr+1 stage AFTER a full compute phase hid its latency.
        __syncthreads();
    }

    // ---- l: sum across quads (q = mt*16 + l15 lives in 4 quad-copies) ----
    #pragma unroll
    for (int mt = 0; mt < 2; mt++) {
        float l = l_r[mt];
        l += __shfl_xor(l, 16);
        l += __shfl_xor(l, 32);
        l_r[mt] = l;
    }

    // ---- group merge via dead LDS: OM f32[128][65] (padded), LM[128] ----
    float* OM = (float*)sMEM;             // 33280 B
    float* LM = (float*)(sMEM + 33280);   // 512 B
    if (g == 1) {
        #pragma unroll
        for (int mt = 0; mt < 2; mt++) {
            int row = wl * 32 + mt * 16 + l15;
            if (quad == 0) LM[row] = l_r[mt];
            #pragma unroll
            for (int nt = 0; nt < 4; nt++)
                #pragma unroll
                for (int r = 0; r < 4; r++)
                    OM[row * 65 + nt * 16 + quad * 4 + r] = O[mt][nt][r];
        }
    }
    __syncthreads();
    if (g == 0) {
        #pragma unroll
        for (int mt = 0; mt < 2; mt++) {
            int row = wl * 32 + mt * 16 + l15;
            float inv = 1.0f / fmaxf(l_r[mt] + LM[row], 1e-30f);
            int qg = qblk * QBLK + row;
            unsigned short* op = Op + (size_t)(b * T_SEQ + qg) * DMODEL + h * DKH;
            #pragma unroll
            for (int nt = 0; nt < 4; nt++) {
                ushort4 w;
                w.x = f2bf((O[mt][nt][0] + OM[row * 65 + nt * 16 + quad * 4 + 0]) * inv);
                w.y = f2bf((O[mt][nt][1] + OM[row * 65 + nt * 16 + quad * 4 + 1]) * inv);
                w.z = f2bf((O[mt][nt][2] + OM[row * 65 + nt * 16 + quad * 4 + 2]) * inv);
                w.w = f2bf((O[mt][nt][3] + OM[row * 65 + nt * 16 + quad * 4 + 3]) * inv);
                *(ushort4*)&op[nt * 16 + quad * 4] = w;
            }
        }
    }
}

// ---------------- legacy fp32-staging GEMM (fallback path only) ----------------
template<int A_BF16, int W_BF16, int C_MODE>
__global__ __launch_bounds__(256) void gemm_bt_cvt(
    const void* __restrict__ A_, const void* __restrict__ W_,
    const float* __restrict__ bias, void* __restrict__ C_,
    int M, int N, int K)
{
    __shared__ __align__(16) unsigned short sA[128 * LDT];
    __shared__ __align__(16) unsigned short sB[128 * LDT];
    const int tid  = threadIdx.x;
    const int wave = tid >> 6, lane = tid & 63;
    const int quad = lane >> 4, l15 = lane & 15;
    const int m0 = blockIdx.y * 128, n0 = blockIdx.x * 128;
    const int wm = (wave & 1) * 64, wn = (wave >> 1) * 64;
    f32x4 acc[4][4] = {};
    for (int k0 = 0; k0 < K; k0 += 64) {
        __syncthreads();
        #pragma unroll
        for (int i = 0; i < 4; i++) {
            int c = tid + 256 * i;
            int row = c >> 3, koff = (c & 7) * 8;
            if (A_BF16)
                *(uint4*)&sA[row * LDT + koff] =
                    *(const uint4*)&((const unsigned short*)A_)[(size_t)(m0 + row) * K + k0 + koff];
            else
                *(uint4*)&sA[row * LDT + koff] =
                    cvt8((const float*)A_ + (size_t)(m0 + row) * K + k0 + koff);
            if (W_BF16)
                *(uint4*)&sB[row * LDT + koff] =
                    *(const uint4*)&((const unsigned short*)W_)[(size_t)(n0 + row) * K + k0 + koff];
            else
                *(uint4*)&sB[row * LDT + koff] =
                    cvt8((const float*)W_ + (size_t)(n0 + row) * K + k0 + koff);
        }
        __syncthreads();
        #pragma unroll
        for (int ks = 0; ks < 2; ks++) {
            bf16x8 af[4], bfr[4];
            #pragma unroll
            for (int mt = 0; mt < 4; mt++)
                af[mt] = *(const bf16x8*)&sA[(wm + mt * 16 + l15) * LDT + ks * 32 + quad * 8];
            #pragma unroll
            for (int nt = 0; nt < 4; nt++)
                bfr[nt] = *(const bf16x8*)&sB[(wn + nt * 16 + l15) * LDT + ks * 32 + quad * 8];
            #pragma unroll
            for (int mt = 0; mt < 4; mt++)
                #pragma unroll
                for (int nt = 0; nt < 4; nt++)
                    acc[mt][nt] = __builtin_amdgcn_mfma_f32_16x16x32_bf16(
                        af[mt], bfr[nt], acc[mt][nt], 0, 0, 0);
        }
    }
    if (C_MODE == 2) {
        #pragma unroll
        for (int mt = 0; mt < 4; mt++)
            #pragma unroll
            for (int r = 0; r < 4; r++) {
                int m = m0 + wm + mt * 16 + quad * 4 + r;
                float bm = bias[m];
                #pragma unroll
                for (int nt = 0; nt < 4; nt++) {
                    int n = n0 + wn + nt * 16 + l15;
                    int bb = n >> 11, t = n & 2047;
                    ((unsigned short*)C_)[((size_t)bb * 1024 + m) * 2048 + t] =
                        f2bf(acc[mt][nt][r] + bm);
                }
            }
    } else {
        #pragma unroll
        for (int nt = 0; nt < 4; nt++) {
            int n = n0 + wn + nt * 16 + l15;
            float bv = bias[n];
            #pragma unroll
            for (int mt = 0; mt < 4; mt++)
                #pragma unroll
                for (int r = 0; r < 4; r++) {
                    int m = m0 + wm + mt * 16 + quad * 4 + r;
                    float val = acc[mt][nt][r] + bv;
                    if (C_MODE == 1) ((float*)C_)[(size_t)m * N + n] = val;
                    else ((unsigned short*)C_)[(size_t)m * N + n] = f2bf(val);
                }
        }
    }
}

extern "C" void kernel_launch(void* const* d_in, const int* in_sizes, int n_in,
                              void* d_out, int out_size, void* d_ws, size_t ws_size,
                              hipStream_t stream)
{
    const float* q  = (const float*)d_in[0];
    const float* k  = (const float*)d_in[1];
    const float* v  = (const float*)d_in[2];
    const int*   mk = (const int*)d_in[3];
    const float* Wq = (const float*)d_in[4];
    const float* bq = (const float*)d_in[5];
    const float* Wk = (const float*)d_in[6];
    const float* bk = (const float*)d_in[7];
    const float* Wv = (const float*)d_in[8];
    const float* bv = (const float*)d_in[9];
    const float* Wo = (const float*)d_in[10];
    const float* bo = (const float*)d_in[11];
    float* out = (float*)d_out;

    unsigned short* wsb = (unsigned short*)d_ws;
    const dim3 gA(T_SEQ / QBLK, NHEAD, B_SZ);   // 16 x 16 x 2 = 512 blocks

    if (ws_size >= (size_t)64 * 1024 * 1024) {
        // Path A: pre-convert to bf16; m97-style global_load_lds GEMMs.
        unsigned short* Qb  = wsb;
        unsigned short* Kb  = wsb + INP_E;
        unsigned short* Vb  = wsb + 2 * INP_E;
        unsigned short* Wqb = wsb + 3 * INP_E;
        unsigned short* Wkb = wsb + 3 * INP_E + W_E;
        unsigned short* Wvb = wsb + 3 * INP_E + 2 * W_E;
        unsigned short* Wob = wsb + 3 * INP_E + 3 * W_E;
        unsigned short* Qp  = wsb + 4 * INP_E;
        unsigned short* Kp  = wsb + 5 * INP_E;
        unsigned short* Vt  = wsb + 6 * INP_E;
        unsigned short* AO  = wsb + 7 * INP_E;       // end = 64MB

        cvt_all<<<2048, 256, 0, stream>>>(q, k, v, Wq, Wk, Wv, Wo, wsb);
        gemm_qkv<<<dim3(256, 1, 3), 256, 0, stream>>>(
            Qb, Kb, Vb, Wqb, Wkb, Wvb, bq, bk, bv, Qp, Kp, Vt);
        attn_kernel<<<gA, 512, 0, stream>>>(Qp, Kp, Vt, mk, AO);
        gemm_o<<<dim3(512, 1, 1), 256, 0, stream>>>(AO, Wob, bo, out);
    } else {
        // Path C fallback: in-GEMM convert (32MB ws), legacy kernels.
        unsigned short* Qp = wsb;
        unsigned short* Kp = wsb + INP_E;
        unsigned short* Vt = wsb + 2 * INP_E;
        unsigned short* AO = wsb + 3 * INP_E;
        const dim3 gN(DMODEL / 128, M_ROWS / 128);
        const dim3 gV(M_ROWS / 128, DMODEL / 128);
        gemm_bt_cvt<0, 0, 0><<<gN, 256, 0, stream>>>(q, Wq, bq, Qp, M_ROWS, DMODEL, DMODEL);
        gemm_bt_cvt<0, 0, 0><<<gN, 256, 0, stream>>>(k, Wk, bk, Kp, M_ROWS, DMODEL, DMODEL);
        gemm_bt_cvt<0, 0, 2><<<gV, 256, 0, stream>>>(Wv, v, bv, Vt, DMODEL, M_ROWS, DMODEL);
        attn_kernel<<<gA, 512, 0, stream>>>(Qp, Kp, Vt, mk, AO);
        gemm_bt_cvt<1, 0, 1><<<gN, 256, 0, stream>>>(AO, Wo, bo, out, M_ROWS, DMODEL, DMODEL);
    }
}